// Round 21
// baseline (25.810 us; speedup 1.0000x reference)
//
#include <hip/hip_runtime.h>

// ============================================================================
// ROUND 21 PROBE: R20 (best-known, 15.40us) enqueued TWICE in the timed
// graph. marginal = dur(2x) - 15.40 separates true exec from fixed
// graph-replay overhead on the CURRENT kernel (R6 measured 5.2us on the old
// kernel; R9's REP-probe suggested ~1us — this decides plateau vs continue).
// Both launches idempotent -> correctness unaffected. R22 reverts to single.
// ============================================================================

#define NN 1024
#define DD 64
#define NF 11
#define TI 8
#define BT 1024

typedef float vfloat4 __attribute__((ext_vector_type(4)));

__global__ __launch_bounds__(BT, 8) void featuresim_kernel(
    const float* __restrict__ x,
    const int* __restrict__ x_lengths,
    const float* __restrict__ fimp,
    float* __restrict__ out)
{
    const int tid = threadIdx.x;
    const int b   = blockIdx.x >> 7;            // 128 row-groups per batch
    const int i0  = (blockIdx.x & 127) * TI;
    const int len = x_lengths[b];

    const bool wave_dead = (tid & ~63) >= len;

    __shared__ float partials[TI][BT];    // 32 KiB -> 2 blocks/CU co-resident

    if (wave_dead) {
        if ((tid & ~255) < len) {
            #pragma unroll
            for (int r = 0; r < TI; ++r)
                partials[r][tid] = 0.0f;
        }
    } else {
        float fi[NF];
        #pragma unroll
        for (int k = 0; k < NF; ++k) fi[k] = fimp[k];

        float fj[NF];
        {
            const float4* p = reinterpret_cast<const float4*>(
                x + (size_t)(b * NN + tid) * DD);
            float4 a = p[0], c = p[1], d = p[2];
            fj[0] = a.x; fj[1] = a.y; fj[2]  = a.z; fj[3] = a.w;
            fj[4] = c.x; fj[5] = c.y; fj[6]  = c.z; fj[7] = c.w;
            fj[8] = d.x; fj[9] = d.y; fj[10] = d.z;
        }
        const bool valid = tid < len;

        #pragma unroll
        for (int r = 0; r < TI; ++r) {
            const float* qp = x + (size_t)(b * NN + i0 + r) * DD;
            float s = 0.0f;
            #pragma unroll
            for (int k = 0; k < NF; ++k) {
                float d = qp[k] - fj[k];
                s = fmaf(-fabsf(d), fi[k], s);
            }
            float val = (s > -1.0f) ? s : 0.0f;
            partials[r][tid] = valid ? __expf(val) : 0.0f;
        }
    }
    __syncthreads();

    const int lane = tid & 63;
    const int wid  = tid >> 6;
    if (wid < TI) {
        float4 v[4];
        float s = 0.0f;
        #pragma unroll
        for (int m = 0; m < 4; ++m) {
            if (256 * m < len) {
                v[m] = *reinterpret_cast<const float4*>(
                    &partials[wid][lane * 4 + 256 * m]);
            } else {
                v[m] = make_float4(0.0f, 0.0f, 0.0f, 0.0f);
            }
            s += (v[m].x + v[m].y) + (v[m].z + v[m].w);
        }
        #pragma unroll
        for (int off = 32; off >= 1; off >>= 1)
            s += __shfl_xor(s, off, 64);

        const float inv = __builtin_amdgcn_rcpf(s);
        vfloat4* rowp = reinterpret_cast<vfloat4*>(
            out + (size_t)(b * NN + i0 + wid) * NN);
        #pragma unroll
        for (int m = 0; m < 4; ++m) {
            vfloat4 o = { v[m].x * inv, v[m].y * inv,
                          v[m].z * inv, v[m].w * inv };
            __builtin_nontemporal_store(o, &rowp[lane + 64 * m]);
        }
    }
}

extern "C" void kernel_launch(void* const* d_in, const int* in_sizes, int n_in,
                              void* d_out, int out_size, void* d_ws, size_t ws_size,
                              hipStream_t stream) {
    const float* x    = (const float*)d_in[0];
    const int*   xlen = (const int*)d_in[1];
    const float* fimp = (const float*)d_in[2];
    float*       out  = (float*)d_out;

    const int B = in_sizes[1];                  // 8
    dim3 grid(B * (NN / TI));                   // 1024 blocks = 2 generations
    dim3 block(BT);
    // PROBE: two identical, idempotent launches in the timed graph.
    featuresim_kernel<<<grid, block, 0, stream>>>(x, xlen, fimp, out);
    featuresim_kernel<<<grid, block, 0, stream>>>(x, xlen, fimp, out);
}

// Round 22
// 15.336 us; speedup vs baseline: 1.6829x; 1.6829x over previous
//
#include <hip/hip_runtime.h>

#define NN 1024
#define DD 64
#define NF 11
#define TI 8
#define BT 1024

typedef float vfloat4 __attribute__((ext_vector_type(4)));  // native clang
// vector: __builtin_nontemporal_store rejects HIP's struct-based float4.

// FINAL (R20 restored after the R21 2x-probe): 15.40us measured; true exec
// ~10.4us vs ~5.0us fixed graph-replay overhead (R21 probe), against a
// ~10us structural floor (5.3us write-stream + ramp + VALU + reduce).
//
// Mechanism ledger (25.4 -> 15.4us):
//  +2-generation dispatch (gen-1 store drain hides under gen-2 compute) -0.7
//  +wave-dead skip (~47% masked lanes, wave-uniform branch)            -1.2
//  +row-owning epilogue (1 barrier, desync'd reducer waves)            -0.4
//  +nontemporal stores (33.5MB write-once bypasses 32MB L2)            -1.5
// Nulled: q-staging, occupancy scaling, barrier re-phasing x3, fj
// coalescing, store hoisting, asym split, 4 generations.
//
// Softmax-without-max is exact here: valid scores are in (-1, 0], masked
// keys contribute exactly +0.0, len >= 1 so every row-sum > 0.
__global__ __launch_bounds__(BT, 8) void featuresim_kernel(
    const float* __restrict__ x,
    const int* __restrict__ x_lengths,
    const float* __restrict__ fimp,
    float* __restrict__ out)
{
    const int tid = threadIdx.x;
    const int b   = blockIdx.x >> 7;            // 128 row-groups per batch
    const int i0  = (blockIdx.x & 127) * TI;
    const int len = x_lengths[b];

    // wave-uniform: this wave's 64 keys are all masked -> all outputs 0
    const bool wave_dead = (tid & ~63) >= len;

    __shared__ float partials[TI][BT];    // 32 KiB -> 2 blocks/CU co-resident

    if (wave_dead) {
        // zero partials ONLY for chunks the reducer will read; the epilogue
        // writes the full row (zeros included), so no out stores here.
        if ((tid & ~255) < len) {
            #pragma unroll
            for (int r = 0; r < TI; ++r)
                partials[r][tid] = 0.0f;
        }
    } else {
        float fi[NF];                     // uniform -> SGPRs
        #pragma unroll
        for (int k = 0; k < NF; ++k) fi[k] = fimp[k];

        float fj[NF];                     // this thread's key row j = tid
        {
            const float4* p = reinterpret_cast<const float4*>(
                x + (size_t)(b * NN + tid) * DD);
            float4 a = p[0], c = p[1], d = p[2];
            fj[0] = a.x; fj[1] = a.y; fj[2]  = a.z; fj[3] = a.w;
            fj[4] = c.x; fj[5] = c.y; fj[6]  = c.z; fj[7] = c.w;
            fj[8] = d.x; fj[9] = d.y; fj[10] = d.z;
        }
        const bool valid = tid < len;     // partial wave masks per-lane

        #pragma unroll
        for (int r = 0; r < TI; ++r) {
            const float* qp = x + (size_t)(b * NN + i0 + r) * DD;  // s_load
            float s = 0.0f;
            #pragma unroll
            for (int k = 0; k < NF; ++k) {
                float d = qp[k] - fj[k];
                s = fmaf(-fabsf(d), fi[k], s);   // -abs() via VOP3 input mod
            }
            float val = (s > -1.0f) ? s : 0.0f;
            partials[r][tid] = valid ? __expf(val) : 0.0f;
        }
    }
    __syncthreads();                      // the ONLY barrier (no stores before)

    // ---- epilogue: wave w owns row w end-to-end; waves 8-15 retire now
    const int lane = tid & 63;
    const int wid  = tid >> 6;
    if (wid < TI) {
        float4 v[4];
        float s = 0.0f;
        #pragma unroll
        for (int m = 0; m < 4; ++m) {
            if (256 * m < len) {          // wave-uniform; skipped chunks all 0
                v[m] = *reinterpret_cast<const float4*>(
                    &partials[wid][lane * 4 + 256 * m]);
            } else {
                v[m] = make_float4(0.0f, 0.0f, 0.0f, 0.0f);
            }
            s += (v[m].x + v[m].y) + (v[m].z + v[m].w);
        }
        #pragma unroll
        for (int off = 32; off >= 1; off >>= 1)
            s += __shfl_xor(s, off, 64);

        const float inv = __builtin_amdgcn_rcpf(s);
        vfloat4* rowp = reinterpret_cast<vfloat4*>(
            out + (size_t)(b * NN + i0 + wid) * NN);
        #pragma unroll
        for (int m = 0; m < 4; ++m) {
            vfloat4 o = { v[m].x * inv, v[m].y * inv,
                          v[m].z * inv, v[m].w * inv };
            __builtin_nontemporal_store(o, &rowp[lane + 64 * m]);  // nt
        }
    }
    // kernel ends with stores in flight -> drain overlaps the next generation
}

extern "C" void kernel_launch(void* const* d_in, const int* in_sizes, int n_in,
                              void* d_out, int out_size, void* d_ws, size_t ws_size,
                              hipStream_t stream) {
    const float* x    = (const float*)d_in[0];
    const int*   xlen = (const int*)d_in[1];
    const float* fimp = (const float*)d_in[2];
    float*       out  = (float*)d_out;

    const int B = in_sizes[1];                  // 8
    dim3 grid(B * (NN / TI));                   // 1024 blocks = 2 generations
    dim3 block(BT);
    featuresim_kernel<<<grid, block, 0, stream>>>(x, xlen, fimp, out);
}